// Round 2
// 515.656 us; speedup vs baseline: 1.3927x; 1.3927x over previous
//
#include <hip/hip_runtime.h>

#define NPOS (16*128*128)   // B*H*W = 262144
#define HWN  16384          // H*W

typedef float v2f __attribute__((ext_vector_type(2)));

// workspace float offsets
#define WS_WMUT  0          // [152][128] transposed Wmu (row r = input channel, col o = output)
#define WS_WSIGT 19456      // [152][8]   transposed Wsig
#define WS_WPI   20672      // [8][16]
#define WS_BPI   20800      // [8]
#define WS_BMU   20808      // [128]
#define WS_BSIG  20936      // [8]
#define WS_WG    20944      // [8]
#define WS_BG    20952      // [1]
#define WS_TOTAL 20953

__global__ __launch_bounds__(256) void prep_weights(
    const float* __restrict__ Wpi, const float* __restrict__ bpi,
    const float* __restrict__ Wmu, const float* __restrict__ bmu,
    const float* __restrict__ Wsig, const float* __restrict__ bsig,
    const float* __restrict__ Wg,  const float* __restrict__ bg,
    float* __restrict__ ws)
{
  int i = blockIdx.x*256 + threadIdx.x;
  if (i < 19456){ int c = i >> 7, o = i & 127; ws[WS_WMUT + i] = Wmu[o*152 + c]; return; }
  i -= 19456;
  if (i < 1216){ int c = i >> 3, j = i & 7; ws[WS_WSIGT + i] = Wsig[j*152 + c]; return; }
  i -= 1216;
  if (i < 128){ ws[WS_WPI + i] = Wpi[i]; return; }
  i -= 128;
  if (i < 8){ ws[WS_BPI + i] = bpi[i]; return; }
  i -= 8;
  if (i < 128){ ws[WS_BMU + i] = bmu[i]; return; }
  i -= 128;
  if (i < 8){ ws[WS_BSIG + i] = bsig[i]; return; }
  i -= 8;
  if (i < 8){ ws[WS_WG + i] = Wg[i]; return; }
  i -= 8;
  if (i < 1){ ws[WS_BG] = bg[0]; }
}

__device__ __forceinline__ v2f pkfma(v2f a, v2f b, v2f c){
#if __has_builtin(__builtin_elementwise_fma)
  return __builtin_elementwise_fma(a, b, c);
#else
  v2f r; r.x = __builtin_fmaf(a.x, b.x, c.x); r.y = __builtin_fmaf(a.y, b.y, c.y); return r;
#endif
}

// Fully fused: single streaming pass over mu computes BOTH dist1 (density) and
// the mu-contribution of the mu_new matvec, with all 128 output accumulators
// resident in VGPRs (64 x v2f). mu is read from HBM exactly once (was 5x:
// 1 dist pass + 4 kc-chunk re-streams).  launch_bounds(256,2): VGPR cap 256,
// 2 waves/SIMD — compute-per-load ratio (64 pk-FMA / 4B load) carries the
// latency hiding instead of occupancy.
__global__ __launch_bounds__(256, 2) void gmm_fused(
    const float* __restrict__ x,
    const float* __restrict__ pi,
    const float* __restrict__ sigma,
    const float* __restrict__ mu,
    const float* __restrict__ ws,
    float* __restrict__ out)
{
  const int p  = blockIdx.x*256 + threadIdx.x;
  const int b  = p >> 14;
  const int hw = p & (HWN-1);

  const float* xb  = x  + b*262144 + hw;   // [b][c][hw], c stride HWN
  const float* mub = mu + b*2097152 + hw;  // [b][m][hw], m stride HWN

  // ---- load x ----
  float xv[16];
  #pragma unroll
  for (int c = 0; c < 16; ++c) xv[c] = xb[c*HWN];

  // ---- init mu_new accumulators: bias + x-part ----
  const float* WmuT = ws + WS_WMUT;
  const float* bmu  = ws + WS_BMU;
  v2f a2[64];
  #pragma unroll
  for (int j = 0; j < 64; ++j){ a2[j].x = bmu[2*j]; a2[j].y = bmu[2*j+1]; }
  #pragma unroll
  for (int c = 0; c < 16; ++c){
    v2f vv; vv.x = xv[c]; vv.y = xv[c];
    const v2f* w2 = (const v2f*)(WmuT + c*128);
    #pragma unroll
    for (int j = 0; j < 64; ++j) a2[j] = pkfma(w2[j], vv, a2[j]);
  }

  // ---- single fused streaming pass over mu: dist1[k] + matvec mu-part ----
  float dist1[8];
  #pragma unroll
  for (int k = 0; k < 8; ++k){
    float mv[16];
    #pragma unroll
    for (int c = 0; c < 16; ++c) mv[c] = mub[(k*16 + c)*HWN];
    float d = 0.f;
    #pragma unroll
    for (int c = 0; c < 16; ++c){
      float t = xv[c] - mv[c];
      d = __builtin_fmaf(t, t, d);
      v2f vv; vv.x = mv[c]; vv.y = mv[c];
      const v2f* w2 = (const v2f*)(WmuT + (16 + k*16 + c)*128);
      #pragma unroll
      for (int j = 0; j < 64; ++j) a2[j] = pkfma(w2[j], vv, a2[j]);
    }
    dist1[k] = d;
  }

  // ---- pi, sigma loads (needed only from here on) ----
  float piv[8], s2v[8];
  #pragma unroll
  for (int k = 0; k < 8; ++k){
    piv[k] = pi[b*131072 + k*HWN + hw];
    float s = sigma[b*131072 + k*HWN + hw];
    s2v[k] = s*s;
  }

  // ---- density, alpha, rho ----
  float alphav[8], rhov[8];
  #pragma unroll
  for (int k = 0; k < 8; ++k){
    float p1 = 6.2831853071795864f * s2v[k];
    float p2 = p1*p1, p4 = p2*p2, p8 = p4*p4;
    float dens = __expf(-0.5f * dist1[k] / s2v[k]) / p8;
    alphav[k] = piv[k] * dens;
    rhov[k]   = alphav[k] * dens;
  }

  // ---- rho-part of mu_new matvec (rows 144..151) ----
  #pragma unroll
  for (int r = 0; r < 8; ++r){
    v2f vv; vv.x = rhov[r]; vv.y = rhov[r];
    const v2f* w2 = (const v2f*)(WmuT + (144 + r)*128);
    #pragma unroll
    for (int j = 0; j < 64; ++j) a2[j] = pkfma(w2[j], vv, a2[j]);
  }

  // ---- pi_new = softmax(Wpi @ [pi, alpha] + bpi) ----
  const float* Wpi = ws + WS_WPI;
  const float* bpi = ws + WS_BPI;
  float logit[8], mx = -1e30f;
  #pragma unroll
  for (int j = 0; j < 8; ++j){
    float a = bpi[j];
    #pragma unroll
    for (int k = 0; k < 8; ++k) a = __builtin_fmaf(Wpi[j*16 + k],     piv[k],    a);
    #pragma unroll
    for (int k = 0; k < 8; ++k) a = __builtin_fmaf(Wpi[j*16 + 8 + k], alphav[k], a);
    logit[j] = a;
    mx = fmaxf(mx, a);
  }
  float pin[8], ssum = 0.f;
  #pragma unroll
  for (int j = 0; j < 8; ++j){ pin[j] = __expf(logit[j] - mx); ssum += pin[j]; }
  float rs = 1.f / ssum;
  float* out_pi = out + b*131072 + hw;
  #pragma unroll
  for (int j = 0; j < 8; ++j){
    pin[j] *= rs;
    __builtin_nontemporal_store(pin[j], &out_pi[j*HWN]);
  }

  // ---- sigma accumulators: bias + x-part + rho-part ----
  const float* WsigT = ws + WS_WSIGT;
  float sacc[8];
  #pragma unroll
  for (int j = 0; j < 8; ++j) sacc[j] = (ws + WS_BSIG)[j];
  #pragma unroll
  for (int c = 0; c < 16; ++c){
    float v = xv[c];
    #pragma unroll
    for (int j = 0; j < 8; ++j) sacc[j] = __builtin_fmaf(WsigT[c*8 + j], v, sacc[j]);
  }
  #pragma unroll
  for (int r = 0; r < 8; ++r){
    float v = rhov[r];
    #pragma unroll
    for (int j = 0; j < 8; ++j) sacc[j] = __builtin_fmaf(WsigT[(144 + r)*8 + j], v, sacc[j]);
  }

  // ---- epilogue: relu, store mu_new, dist2, sigma accumulation ----
  float* out_mu = out + 2097152 + b*2097152 + hw;
  float dist2v[8];
  #pragma unroll
  for (int k = 0; k < 8; ++k) dist2v[k] = 0.f;
  #pragma unroll
  for (int j = 0; j < 128; ++j){
    float raw = (j & 1) ? a2[j>>1].y : a2[j>>1].x;
    float mn = fmaxf(raw, 0.f);
    __builtin_nontemporal_store(mn, &out_mu[j*HWN]);
    float t = xv[j & 15] - mn;
    dist2v[j>>4] = __builtin_fmaf(t, t, dist2v[j>>4]);
    #pragma unroll
    for (int jj = 0; jj < 8; ++jj)
      sacc[jj] = __builtin_fmaf(WsigT[(16 + j)*8 + jj], mn, sacc[jj]);
  }

  // ---- sigma_new, dens2, gamma ----
  const float* Wg = ws + WS_WG;
  float g = ws[WS_BG];
  float* out_sig = out + 35651584 + b*131072 + hw;
  #pragma unroll
  for (int k = 0; k < 8; ++k){
    float sn = __expf(fmaxf(sacc[k], 0.f));
    __builtin_nontemporal_store(sn, &out_sig[k*HWN]);
    float s2 = sn*sn;
    float p1 = 6.2831853071795864f * s2;
    float p2 = p1*p1, p4 = p2*p2, p8 = p4*p4;
    float dn2 = __expf(-0.5f * dist2v[k] / s2) / p8;
    g = __builtin_fmaf(Wg[k], pin[k] * dn2, g);
  }
  float gv = 1.f / (1.f + __expf(-g));
  __builtin_nontemporal_store(gv, &out[37748736 + p]);
}

extern "C" void kernel_launch(void* const* d_in, const int* in_sizes, int n_in,
                              void* d_out, int out_size, void* d_ws, size_t ws_size,
                              hipStream_t stream)
{
  const float* x    = (const float*)d_in[0];
  const float* pi   = (const float*)d_in[1];
  const float* mu   = (const float*)d_in[2];
  const float* sg   = (const float*)d_in[3];
  const float* Wpi  = (const float*)d_in[4];
  const float* bpi  = (const float*)d_in[5];
  const float* Wmu  = (const float*)d_in[6];
  const float* bmu  = (const float*)d_in[7];
  const float* Wsig = (const float*)d_in[8];
  const float* bsig = (const float*)d_in[9];
  const float* Wg   = (const float*)d_in[10];
  const float* bg   = (const float*)d_in[11];
  float* ws  = (float*)d_ws;
  float* out = (float*)d_out;

  prep_weights<<<(WS_TOTAL + 255)/256, 256, 0, stream>>>(
      Wpi, bpi, Wmu, bmu, Wsig, bsig, Wg, bg, ws);
  gmm_fused<<<NPOS/256, 256, 0, stream>>>(x, pi, sg, mu, ws, out);
}